// Round 6
// baseline (564.168 us; speedup 1.0000x reference)
//
#include <hip/hip_runtime.h>

#define MAXNB 1024  // max dst-buckets (128 nodes each) -> supports n <= 131072

typedef __attribute__((ext_vector_type(8))) short bf8;    // 8 bf16 (4 VGPRs)
typedef __attribute__((ext_vector_type(4))) float f32x4;  // MFMA C/D

// pack two fp32 -> two bf16 (RNE) in one uint (a = low = even channel)
__device__ __forceinline__ unsigned pack_bf16x2(float a, float b) {
  unsigned ua = __float_as_uint(a);
  ua = (ua + 0x7fffu + ((ua >> 16) & 1u)) >> 16;
  unsigned ub = __float_as_uint(b);
  ub = (ub + 0x7fffu + ((ub >> 16) & 1u)) >> 16;
  return ua | (ub << 16);
}

// ---- W prep: fp32 [128k][128c] -> bf16 B-fragments for 16x16x32 MFMA ------
__global__ __launch_bounds__(256) void k_wprep(const float* __restrict__ W,
                                               uint4* __restrict__ Wf) {
  const int t = blockIdx.x * 256 + threadIdx.x;  // 0..2047
  const int frag = t >> 6, lane = t & 63;
  const int ct = frag >> 2, kc = frag & 3;
  const int col = ct * 16 + (lane & 15);
  const int k0 = kc * 32 + (lane >> 4) * 8;
  unsigned p[4];
#pragma unroll
  for (int j = 0; j < 4; ++j)
    p[j] = pack_bf16x2(W[(k0 + 2 * j) * 128 + col],
                       W[(k0 + 2 * j + 1) * 128 + col]);
  Wf[t] = make_uint4(p[0], p[1], p[2], p[3]);
}

// ---- MFMA GEMM: H(bf16) = X[n,128] @ W[128,128], fused alpha dots ---------
__global__ __launch_bounds__(256) void k_gemm(
    const float* __restrict__ X, const uint4* __restrict__ Wf,
    unsigned* __restrict__ Hb, int n, const float* __restrict__ bnss,
    const float* __restrict__ a_src, const float* __restrict__ a_dst,
    float* __restrict__ as_, float* __restrict__ ad_) {
  __shared__ float stag[64 * 132];  // 33792 B
  const int tid = threadIdx.x;
  const int w = tid >> 6, lane = tid & 63;
  const int q = lane >> 4, nl = lane & 15;
  const long row0 = (long)blockIdx.x * 64;
  long rowA = row0 + w * 16 + nl;
  if (rowA >= n) rowA = n - 1;  // clamp; stores are guarded

  bf8 a[4];
#pragma unroll
  for (int kc = 0; kc < 4; ++kc) {
    const float* p = X + rowA * 128 + kc * 32 + q * 8;
    float4 v0 = *(const float4*)p;
    float4 v1 = *(const float4*)(p + 4);
    if (bnss) {  // fold previous layer's BN+ReLU: x = relu(x*sc+sh)
      const int kb = kc * 32 + q * 8;
      float4 s0 = *(const float4*)(bnss + kb);
      float4 s1 = *(const float4*)(bnss + kb + 4);
      float4 h0 = *(const float4*)(bnss + 128 + kb);
      float4 h1 = *(const float4*)(bnss + 128 + kb + 4);
      v0.x = fmaxf(fmaf(v0.x, s0.x, h0.x), 0.f);
      v0.y = fmaxf(fmaf(v0.y, s0.y, h0.y), 0.f);
      v0.z = fmaxf(fmaf(v0.z, s0.z, h0.z), 0.f);
      v0.w = fmaxf(fmaf(v0.w, s0.w, h0.w), 0.f);
      v1.x = fmaxf(fmaf(v1.x, s1.x, h1.x), 0.f);
      v1.y = fmaxf(fmaf(v1.y, s1.y, h1.y), 0.f);
      v1.z = fmaxf(fmaf(v1.z, s1.z, h1.z), 0.f);
      v1.w = fmaxf(fmaf(v1.w, s1.w, h1.w), 0.f);
    }
    union { uint4 u; bf8 v; } cv;
    cv.u = make_uint4(pack_bf16x2(v0.x, v0.y), pack_bf16x2(v0.z, v0.w),
                      pack_bf16x2(v1.x, v1.y), pack_bf16x2(v1.z, v1.w));
    a[kc] = cv.v;
  }

  f32x4 acc[8];
#pragma unroll
  for (int ct = 0; ct < 8; ++ct) {
    f32x4 c = {0.f, 0.f, 0.f, 0.f};
#pragma unroll
    for (int kc = 0; kc < 4; ++kc) {
      union { uint4 u; bf8 v; } b;
      b.u = Wf[(ct * 4 + kc) * 64 + lane];
      c = __builtin_amdgcn_mfma_f32_16x16x32_bf16(a[kc], b.v, c, 0, 0, 0);
    }
    acc[ct] = c;
  }

  const int lr = w * 16 + q * 4;
#pragma unroll
  for (int ct = 0; ct < 8; ++ct)
#pragma unroll
    for (int r = 0; r < 4; ++r)
      stag[(lr + r) * 132 + ct * 16 + nl] = acc[ct][r];
  __syncthreads();

  {
    const int row = tid >> 2, seg = tid & 3;
    const long grow = row0 + row;
    if (grow < n) {
      float sp = 0.f, dp = 0.f;
      const float* p = &stag[row * 132 + seg * 32];
#pragma unroll
      for (int i = 0; i < 8; ++i) {
        float4 h4 = *(const float4*)(p + i * 4);
        float4 s4 = ((const float4*)a_src)[seg * 8 + i];
        float4 d4 = ((const float4*)a_dst)[seg * 8 + i];
        sp += h4.x * s4.x + h4.y * s4.y + h4.z * s4.z + h4.w * s4.w;
        dp += h4.x * d4.x + h4.y * d4.y + h4.z * d4.z + h4.w * d4.w;
        uint2 o;
        o.x = pack_bf16x2(h4.x, h4.y);
        o.y = pack_bf16x2(h4.z, h4.w);
        ((uint2*)Hb)[grow * 32 + seg * 8 + i] = o;
      }
      as_[grow * 4 + seg] = sp;
      ad_[grow * 4 + seg] = dp;
    }
  }
}

// ---------------- CSR build via dst-bucket binning --------------------------
__global__ __launch_bounds__(256) void k_hist(const int* __restrict__ ei,
                                              int E, int NB,
                                              int* __restrict__ bcnt) {
  __shared__ int hist[MAXNB];
  for (int i = threadIdx.x; i < NB; i += 256) hist[i] = 0;
  __syncthreads();
  const int e0 = blockIdx.x * 4096;
#pragma unroll
  for (int k = 0; k < 16; ++k) {
    int e = e0 + k * 256 + threadIdx.x;
    if (e < E) atomicAdd(&hist[ei[E + e] >> 7], 1);
  }
  __syncthreads();
  for (int i = threadIdx.x; i < NB; i += 256) {
    int c = hist[i];
    if (c) atomicAdd(&bcnt[i], c);
  }
}

__global__ __launch_bounds__(1024) void k_bprefix(const int* __restrict__ bcnt,
                                                  int NB,
                                                  int* __restrict__ bstart,
                                                  int* __restrict__ bcur) {
  __shared__ int sh[1024];
  const int t = threadIdx.x;
  int v = (t < NB) ? bcnt[t] : 0;
  sh[t] = v;
  __syncthreads();
  for (int off = 1; off < 1024; off <<= 1) {
    int u = (t >= off) ? sh[t - off] : 0;
    __syncthreads();
    sh[t] += u;
    __syncthreads();
  }
  if (t < NB) {
    int ex = sh[t] - v;
    bstart[t] = ex;
    bcur[t] = ex;
    if (t == NB - 1) bstart[NB] = sh[t];
  }
}

__global__ __launch_bounds__(256) void k_scatter(const int* __restrict__ ei,
                                                 int E, int NB,
                                                 int* __restrict__ bcur,
                                                 int* __restrict__ packed) {
  __shared__ int hist[MAXNB];
  __shared__ int hbase[MAXNB];
  for (int i = threadIdx.x; i < NB; i += 256) hist[i] = 0;
  __syncthreads();
  const int e0 = blockIdx.x * 4096;
  int myb[16], myv[16];
#pragma unroll
  for (int k = 0; k < 16; ++k) {
    int e = e0 + k * 256 + threadIdx.x;
    myb[k] = -1;
    myv[k] = 0;
    if (e < E) {
      int s = ei[e], d = ei[E + e];
      myb[k] = d >> 7;
      myv[k] = (s << 7) | (d & 127);
      atomicAdd(&hist[myb[k]], 1);
    }
  }
  __syncthreads();
  for (int i = threadIdx.x; i < NB; i += 256) {
    int c = hist[i];
    hbase[i] = c ? atomicAdd(&bcur[i], c) : 0;
    hist[i] = 0;
  }
  __syncthreads();
#pragma unroll
  for (int k = 0; k < 16; ++k) {
    if (myb[k] >= 0) {
      int p = hbase[myb[k]] + atomicAdd(&hist[myb[k]], 1);
      packed[p] = myv[k];
    }
  }
}

__global__ __launch_bounds__(256) void k_local(const int* __restrict__ packed,
                                               const int* __restrict__ bstart,
                                               int n, int* __restrict__ srcs,
                                               int* __restrict__ offs,
                                               int* __restrict__ deg) {
  const int b = blockIdx.x;
  const int node0 = b << 7;
  const int nn = min(128, n - node0);
  const int e0 = bstart[b], e1 = bstart[b + 1];
  __shared__ int dcnt[128], cur[128], scan[128];
  const int tid = threadIdx.x;
  if (tid < 128) dcnt[tid] = 0;
  __syncthreads();
  for (int i = e0 + tid; i < e1; i += 256)
    atomicAdd(&dcnt[packed[i] & 127], 1);
  __syncthreads();
  int v = 0;
  if (tid < 128) {
    v = (tid < nn) ? dcnt[tid] + 1 : 0;  // +1 = self-loop slot
    scan[tid] = v;
  }
  __syncthreads();
  for (int off = 1; off < 128; off <<= 1) {
    int u = 0;
    if (tid < 128 && tid >= off) u = scan[tid - off];
    __syncthreads();
    if (tid < 128) scan[tid] += u;
    __syncthreads();
  }
  if (tid < nn) {
    const int o = e0 + node0 + (scan[tid] - v);  // global CSR offset
    offs[node0 + tid] = o;
    deg[node0 + tid] = dcnt[tid];
    srcs[o] = node0 + tid;  // self-loop first
    cur[tid] = o + 1;
  }
  __syncthreads();
  for (int i = e0 + tid; i < e1; i += 256) {
    const int pv = packed[i];
    const int p = atomicAdd(&cur[pv & 127], 1);
    srcs[p] = pv >> 7;
  }
}

// ---------------- fused GAT aggregation: 16 thr/node, uint4 gathers ---------
// 4 nodes per wave. Thread (within node) t = lane&15: owns channels 8t..8t+7
// (head th = t>>2), edge slot j4 = lane&3 in each 4-edge chunk.
// Chunk prep (srcs -> as_ -> exp) is software-pipelined one chunk ahead.
__global__ __launch_bounds__(256) void k_agg(
    const int* __restrict__ offs, const int* __restrict__ deg,
    const int* __restrict__ srcs, const uint4* __restrict__ Hb,
    const float* __restrict__ as_, const float* __restrict__ ad_,
    float* __restrict__ out, int n) {
  const int node = blockIdx.x * 16 + (threadIdx.x >> 4);
  if (node >= n) return;
  const int lane = threadIdx.x & 63;
  const int t = lane & 15;
  const int th = t >> 2;    // head of my channels
  const int j4 = lane & 3;  // my edge slot per chunk
  const int o0 = offs[node];
  const int dg = deg[node] + 1;  // + self-loop
  const float adv = ad_[node * 4 + th];

  float den = 0.f;
  float acc[8];
#pragma unroll
  for (int i = 0; i < 8; ++i) acc[i] = 0.f;

  // prologue: prep chunk 0
  int s = 0;
  float e = 0.f;
  if (j4 < dg) {
    s = srcs[o0 + j4];
    float l = as_[s * 4 + th] + adv;
    l = l >= 0.f ? l : 0.2f * l;
    e = __expf(fminf(l, 80.f));
  }

  for (int base = 0; base < dg; base += 4) {
    // prefetch next chunk's (s, e)
    int s2 = 0;
    float e2 = 0.f;
    const int jn = base + 4 + j4;
    if (jn < dg) {
      s2 = srcs[o0 + jn];
      float l = as_[s2 * 4 + th] + adv;
      l = l >= 0.f ? l : 0.2f * l;
      e2 = __expf(fminf(l, 80.f));
    }
    den += e;
#pragma unroll
    for (int jj = 0; jj < 4; ++jj) {
      if (base + jj >= dg) break;
      const int ss = __shfl(s, (lane & 48) | jj, 64);
      const float w = __shfl(e, (lane & ~3) | jj, 64);
      const uint4 hv = Hb[(long)ss * 16 + t];
      acc[0] = fmaf(w, __uint_as_float(hv.x << 16), acc[0]);
      acc[1] = fmaf(w, __uint_as_float(hv.x & 0xffff0000u), acc[1]);
      acc[2] = fmaf(w, __uint_as_float(hv.y << 16), acc[2]);
      acc[3] = fmaf(w, __uint_as_float(hv.y & 0xffff0000u), acc[3]);
      acc[4] = fmaf(w, __uint_as_float(hv.z << 16), acc[4]);
      acc[5] = fmaf(w, __uint_as_float(hv.z & 0xffff0000u), acc[5]);
      acc[6] = fmaf(w, __uint_as_float(hv.w << 16), acc[6]);
      acc[7] = fmaf(w, __uint_as_float(hv.w & 0xffff0000u), acc[7]);
    }
    s = s2;
    e = e2;
  }
  // reduce den within the 4-lane head group (lanes nb|(th<<2)|{0..3})
  den += __shfl_xor(den, 1, 64);
  den += __shfl_xor(den, 2, 64);
  const float invden = 1.f / (den + 1e-16f);
  float4 o0v = make_float4(acc[0] * invden, acc[1] * invden, acc[2] * invden,
                           acc[3] * invden);
  float4 o1v = make_float4(acc[4] * invden, acc[5] * invden, acc[6] * invden,
                           acc[7] * invden);
  ((float4*)out)[(long)node * 32 + t * 2] = o0v;
  ((float4*)out)[(long)node * 32 + t * 2 + 1] = o1v;
}

// ---------------- BN stats / fold / apply -----------------------------------
__global__ __launch_bounds__(256) void k_stats(const float* __restrict__ V,
                                               float* __restrict__ stats,
                                               int n) {
  const int tid = threadIdx.x;
  const int c = tid & 127, half = tid >> 7;
  float s = 0.f, s2 = 0.f;
  for (int r = blockIdx.x * 2 + half; r < n; r += gridDim.x * 2) {
    float v = V[(long)r * 128 + c];
    s += v;
    s2 = fmaf(v, v, s2);
  }
  __shared__ float sh[256];
  sh[tid] = s;
  __syncthreads();
  if (half == 0) s += sh[tid + 128];
  __syncthreads();
  sh[tid] = s2;
  __syncthreads();
  if (half == 0) {
    s2 += sh[tid + 128];
    atomicAdd(&stats[c], s);
    atomicAdd(&stats[128 + c], s2);
  }
}

__global__ void k_finalize(const float* __restrict__ stats,
                           const float* __restrict__ gamma,
                           const float* __restrict__ beta,
                           float* __restrict__ ss, float invN) {
  int c = threadIdx.x;  // 128 threads
  float mean = stats[c] * invN;
  float var = stats[128 + c] * invN - mean * mean;
  float sc = gamma[c] * rsqrtf(var + 1e-5f);
  ss[c] = sc;
  ss[128 + c] = beta[c] - mean * sc;
}

__global__ __launch_bounds__(256) void k_bn_apply(
    const float* __restrict__ V, const float* __restrict__ ss,
    const float* __restrict__ skip, float* __restrict__ Y, int total4) {
  const int i = blockIdx.x * 256 + threadIdx.x;
  if (i >= total4) return;
  const int c4 = i & 31;
  float4 v = ((const float4*)V)[i];
  float4 sc = ((const float4*)ss)[c4];
  float4 sh = ((const float4*)ss)[32 + c4];
  float4 s = ((const float4*)skip)[i];
  float4 y;
  y.x = fmaxf(fmaf(v.x, sc.x, sh.x) + s.x, 0.f);
  y.y = fmaxf(fmaf(v.y, sc.y, sh.y) + s.y, 0.f);
  y.z = fmaxf(fmaf(v.z, sc.z, sh.z) + s.z, 0.f);
  y.w = fmaxf(fmaf(v.w, sc.w, sh.w) + s.w, 0.f);
  ((float4*)Y)[i] = y;
}

extern "C" void kernel_launch(void* const* d_in, const int* in_sizes, int n_in,
                              void* d_out, int out_size, void* d_ws,
                              size_t ws_size, hipStream_t stream) {
  const float* x = (const float*)d_in[0];
  const int* ei = (const int*)d_in[1];
  const float* W1 = (const float*)d_in[2];
  const float* a_src1 = (const float*)d_in[3];
  const float* a_dst1 = (const float*)d_in[4];
  // b1 cancels in BN
  const float* gamma1 = (const float*)d_in[6];
  const float* beta1 = (const float*)d_in[7];
  const float* W2 = (const float*)d_in[8];
  const float* a_src2 = (const float*)d_in[9];
  const float* a_dst2 = (const float*)d_in[10];
  // b2 cancels in BN
  const float* gamma2 = (const float*)d_in[12];
  const float* beta2 = (const float*)d_in[13];

  const int n = in_sizes[0] / 128;
  const int E = in_sizes[1] / 2;
  const int EP = E + n;
  const int NB = (n + 127) >> 7;  // dst buckets (<= MAXNB)
  const int EB = (E + 4095) / 4096;

  char* w = (char*)d_ws;
  const size_t szNC = (size_t)n * 128 * sizeof(float);
  unsigned* Hb = (unsigned*)w;  w += (size_t)n * 64 * sizeof(unsigned);
  float* Bagg = (float*)w;      w += szNC;
  float* as_ = (float*)w;       w += (size_t)n * 4 * sizeof(float);
  float* ad_ = (float*)w;       w += (size_t)n * 4 * sizeof(float);
  int* srcs = (int*)w;          w += (size_t)EP * sizeof(int);
  int* packed = (int*)w;        w += (size_t)E * sizeof(int);
  int* deg = (int*)w;           w += (size_t)n * sizeof(int);
  int* offs = (int*)w;          w += (size_t)n * sizeof(int);
  int* bcnt = (int*)w;          w += (size_t)NB * sizeof(int);
  int* bstart = (int*)w;        w += (size_t)(NB + 1) * sizeof(int);
  int* bcur = (int*)w;          w += (size_t)NB * sizeof(int);
  uint4* Wf1 = (uint4*)w;       w += 2048 * sizeof(uint4);
  uint4* Wf2 = (uint4*)w;       w += 2048 * sizeof(uint4);
  float* stats = (float*)w;     w += 256 * sizeof(float);
  float* ss1 = (float*)w;       w += 256 * sizeof(float);
  float* ss2 = (float*)w;       w += 256 * sizeof(float);

  // ---- W fragment prep (once per launch) ----
  k_wprep<<<8, 256, 0, stream>>>(W1, Wf1);
  k_wprep<<<8, 256, 0, stream>>>(W2, Wf2);

  // ---- CSR build (bucket binning; shared by both layers) ----
  hipMemsetAsync(bcnt, 0, (size_t)NB * sizeof(int), stream);
  k_hist<<<EB, 256, 0, stream>>>(ei, E, NB, bcnt);
  k_bprefix<<<1, 1024, 0, stream>>>(bcnt, NB, bstart, bcur);
  k_scatter<<<EB, 256, 0, stream>>>(ei, E, NB, bcur, packed);
  k_local<<<NB, 256, 0, stream>>>(packed, bstart, n, srcs, offs, deg);

  // ---- layer 1 ----
  k_gemm<<<(n + 63) / 64, 256, 0, stream>>>(x, Wf1, Hb, n, nullptr, a_src1,
                                            a_dst1, as_, ad_);
  k_agg<<<(n + 15) / 16, 256, 0, stream>>>(offs, deg, srcs, (const uint4*)Hb,
                                           as_, ad_, Bagg, n);
  hipMemsetAsync(stats, 0, 256 * sizeof(float), stream);
  k_stats<<<256, 256, 0, stream>>>(Bagg, stats, n);
  k_finalize<<<1, 128, 0, stream>>>(stats, gamma1, beta1, ss1,
                                    1.0f / (float)n);

  // ---- layer 2 (BN1+ReLU folded into GEMM2's X load; y1 never stored) ----
  k_gemm<<<(n + 63) / 64, 256, 0, stream>>>(Bagg, Wf2, Hb, n, ss1, a_src2,
                                            a_dst2, as_, ad_);
  k_agg<<<(n + 15) / 16, 256, 0, stream>>>(offs, deg, srcs, (const uint4*)Hb,
                                           as_, ad_, Bagg, n);
  hipMemsetAsync(stats, 0, 256 * sizeof(float), stream);
  k_stats<<<256, 256, 0, stream>>>(Bagg, stats, n);
  k_finalize<<<1, 128, 0, stream>>>(stats, gamma2, beta2, ss2,
                                    1.0f / (float)n);
  k_bn_apply<<<(n * 32 + 255) / 256, 256, 0, stream>>>(Bagg, ss2, x,
                                                       (float*)d_out, n * 32);
}

// Round 7
// 456.217 us; speedup vs baseline: 1.2366x; 1.2366x over previous
//
#include <hip/hip_runtime.h>

#define MAXNB 1024  // max dst-buckets (128 nodes each) -> supports n <= 131072
#define NSLOT 8     // BN stats spread (contention vs redundant-read tradeoff)

typedef __attribute__((ext_vector_type(8))) short bf8;    // 8 bf16 (4 VGPRs)
typedef __attribute__((ext_vector_type(4))) float f32x4;  // MFMA C/D

// pack two fp32 -> two bf16 (RNE) in one uint (a = low = even channel)
__device__ __forceinline__ unsigned pack_bf16x2(float a, float b) {
  unsigned ua = __float_as_uint(a);
  ua = (ua + 0x7fffu + ((ua >> 16) & 1u)) >> 16;
  unsigned ub = __float_as_uint(b);
  ub = (ub + 0x7fffu + ((ub >> 16) & 1u)) >> 16;
  return ua | (ub << 16);
}

// ---- W prep: fp32 [128k][128c] -> bf16 B-fragments for 16x16x32 MFMA ------
// grid 16: blocks 0-7 -> W1/Wf1, blocks 8-15 -> W2/Wf2.
__global__ __launch_bounds__(256) void k_wprep(const float* __restrict__ W1,
                                               uint4* __restrict__ Wf1,
                                               const float* __restrict__ W2,
                                               uint4* __restrict__ Wf2) {
  const int half = blockIdx.x >> 3;
  const float* W = half ? W2 : W1;
  uint4* Wf = half ? Wf2 : Wf1;
  const int t = (blockIdx.x & 7) * 256 + threadIdx.x;  // 0..2047
  const int frag = t >> 6, lane = t & 63;
  const int ct = frag >> 2, kc = frag & 3;
  const int col = ct * 16 + (lane & 15);
  const int k0 = kc * 32 + (lane >> 4) * 8;
  unsigned p[4];
#pragma unroll
  for (int j = 0; j < 4; ++j)
    p[j] = pack_bf16x2(W[(k0 + 2 * j) * 128 + col],
                       W[(k0 + 2 * j + 1) * 128 + col]);
  Wf[t] = make_uint4(p[0], p[1], p[2], p[3]);
}

// ---- MFMA GEMM: H(bf16) = X[n,128] @ W[128,128], fused alpha dots ---------
// If stats!=null: inline BN-finalize (mean/var from NSLOT-spread sums) and
// fold x = relu(x*sc+sh) into the A-fragment load.
__global__ __launch_bounds__(256) void k_gemm(
    const float* __restrict__ X, const uint4* __restrict__ Wf,
    unsigned* __restrict__ Hb, int n, const float* __restrict__ stats,
    const float* __restrict__ gamma, const float* __restrict__ beta,
    float invN, const float* __restrict__ a_src,
    const float* __restrict__ a_dst, float* __restrict__ as_,
    float* __restrict__ ad_) {
  __shared__ float stag[64 * 132];  // 33792 B
  __shared__ float ssl[256];        // BN scale/shift
  const int tid = threadIdx.x;
  if (stats && tid < 128) {
    float s = 0.f, s2 = 0.f;
#pragma unroll
    for (int k = 0; k < NSLOT; ++k) {
      s += stats[k * 256 + tid];
      s2 += stats[k * 256 + 128 + tid];
    }
    float mean = s * invN;
    float var = s2 * invN - mean * mean;
    float sc = gamma[tid] * rsqrtf(var + 1e-5f);
    ssl[tid] = sc;
    ssl[128 + tid] = beta[tid] - mean * sc;
  }
  __syncthreads();

  const int w = tid >> 6, lane = tid & 63;
  const int q = lane >> 4, nl = lane & 15;
  const long row0 = (long)blockIdx.x * 64;
  long rowA = row0 + w * 16 + nl;
  if (rowA >= n) rowA = n - 1;  // clamp; stores are guarded

  bf8 a[4];
#pragma unroll
  for (int kc = 0; kc < 4; ++kc) {
    const float* p = X + rowA * 128 + kc * 32 + q * 8;
    float4 v0 = *(const float4*)p;
    float4 v1 = *(const float4*)(p + 4);
    if (stats) {  // fold previous layer's BN+ReLU
      const int kb = kc * 32 + q * 8;
      float4 s0 = *(const float4*)&ssl[kb];
      float4 s1 = *(const float4*)&ssl[kb + 4];
      float4 h0 = *(const float4*)&ssl[128 + kb];
      float4 h1 = *(const float4*)&ssl[128 + kb + 4];
      v0.x = fmaxf(fmaf(v0.x, s0.x, h0.x), 0.f);
      v0.y = fmaxf(fmaf(v0.y, s0.y, h0.y), 0.f);
      v0.z = fmaxf(fmaf(v0.z, s0.z, h0.z), 0.f);
      v0.w = fmaxf(fmaf(v0.w, s0.w, h0.w), 0.f);
      v1.x = fmaxf(fmaf(v1.x, s1.x, h1.x), 0.f);
      v1.y = fmaxf(fmaf(v1.y, s1.y, h1.y), 0.f);
      v1.z = fmaxf(fmaf(v1.z, s1.z, h1.z), 0.f);
      v1.w = fmaxf(fmaf(v1.w, s1.w, h1.w), 0.f);
    }
    union { uint4 u; bf8 v; } cv;
    cv.u = make_uint4(pack_bf16x2(v0.x, v0.y), pack_bf16x2(v0.z, v0.w),
                      pack_bf16x2(v1.x, v1.y), pack_bf16x2(v1.z, v1.w));
    a[kc] = cv.v;
  }

  f32x4 acc[8];
#pragma unroll
  for (int ct = 0; ct < 8; ++ct) {
    f32x4 c = {0.f, 0.f, 0.f, 0.f};
#pragma unroll
    for (int kc = 0; kc < 4; ++kc) {
      union { uint4 u; bf8 v; } b;
      b.u = Wf[(ct * 4 + kc) * 64 + lane];
      c = __builtin_amdgcn_mfma_f32_16x16x32_bf16(a[kc], b.v, c, 0, 0, 0);
    }
    acc[ct] = c;
  }

  const int lr = w * 16 + q * 4;
#pragma unroll
  for (int ct = 0; ct < 8; ++ct)
#pragma unroll
    for (int r = 0; r < 4; ++r)
      stag[(lr + r) * 132 + ct * 16 + nl] = acc[ct][r];
  __syncthreads();

  {
    const int row = tid >> 2, seg = tid & 3;
    const long grow = row0 + row;
    if (grow < n) {
      float sp = 0.f, dp = 0.f;
      const float* p = &stag[row * 132 + seg * 32];
#pragma unroll
      for (int i = 0; i < 8; ++i) {
        float4 h4 = *(const float4*)(p + i * 4);
        float4 s4 = ((const float4*)a_src)[seg * 8 + i];
        float4 d4 = ((const float4*)a_dst)[seg * 8 + i];
        sp += h4.x * s4.x + h4.y * s4.y + h4.z * s4.z + h4.w * s4.w;
        dp += h4.x * d4.x + h4.y * d4.y + h4.z * d4.z + h4.w * d4.w;
        uint2 o;
        o.x = pack_bf16x2(h4.x, h4.y);
        o.y = pack_bf16x2(h4.z, h4.w);
        ((uint2*)Hb)[grow * 32 + seg * 8 + i] = o;
      }
      as_[grow * 4 + seg] = sp;
      ad_[grow * 4 + seg] = dp;
    }
  }
}

// ---------------- CSR build via dst-bucket binning --------------------------
__global__ __launch_bounds__(256) void k_hist(const int* __restrict__ ei,
                                              int E, int NB,
                                              int* __restrict__ bcnt) {
  __shared__ int hist[MAXNB];
  for (int i = threadIdx.x; i < NB; i += 256) hist[i] = 0;
  __syncthreads();
  const int e0 = blockIdx.x * 4096;
#pragma unroll
  for (int k = 0; k < 16; ++k) {
    int e = e0 + k * 256 + threadIdx.x;
    if (e < E) atomicAdd(&hist[ei[E + e] >> 7], 1);
  }
  __syncthreads();
  for (int i = threadIdx.x; i < NB; i += 256) {
    int c = hist[i];
    if (c) atomicAdd(&bcnt[i], c);
  }
}

__global__ __launch_bounds__(1024) void k_bprefix(const int* __restrict__ bcnt,
                                                  int NB,
                                                  int* __restrict__ bstart,
                                                  int* __restrict__ bcur) {
  __shared__ int sh[1024];
  const int t = threadIdx.x;
  int v = (t < NB) ? bcnt[t] : 0;
  sh[t] = v;
  __syncthreads();
  for (int off = 1; off < 1024; off <<= 1) {
    int u = (t >= off) ? sh[t - off] : 0;
    __syncthreads();
    sh[t] += u;
    __syncthreads();
  }
  if (t < NB) {
    int ex = sh[t] - v;
    bstart[t] = ex;
    bcur[t] = ex;
    if (t == NB - 1) bstart[NB] = sh[t];
  }
}

__global__ __launch_bounds__(256) void k_scatter(const int* __restrict__ ei,
                                                 int E, int NB,
                                                 int* __restrict__ bcur,
                                                 int* __restrict__ packed) {
  __shared__ int hist[MAXNB];
  __shared__ int hbase[MAXNB];
  for (int i = threadIdx.x; i < NB; i += 256) hist[i] = 0;
  __syncthreads();
  const int e0 = blockIdx.x * 4096;
  int myb[16], myv[16];
#pragma unroll
  for (int k = 0; k < 16; ++k) {
    int e = e0 + k * 256 + threadIdx.x;
    myb[k] = -1;
    myv[k] = 0;
    if (e < E) {
      int s = ei[e], d = ei[E + e];
      myb[k] = d >> 7;
      myv[k] = (s << 7) | (d & 127);
      atomicAdd(&hist[myb[k]], 1);
    }
  }
  __syncthreads();
  for (int i = threadIdx.x; i < NB; i += 256) {
    int c = hist[i];
    hbase[i] = c ? atomicAdd(&bcur[i], c) : 0;
    hist[i] = 0;
  }
  __syncthreads();
#pragma unroll
  for (int k = 0; k < 16; ++k) {
    if (myb[k] >= 0) {
      int p = hbase[myb[k]] + atomicAdd(&hist[myb[k]], 1);
      packed[p] = myv[k];
    }
  }
}

__global__ __launch_bounds__(256) void k_local(const int* __restrict__ packed,
                                               const int* __restrict__ bstart,
                                               int n, int* __restrict__ srcs,
                                               int* __restrict__ offs,
                                               int* __restrict__ deg) {
  const int b = blockIdx.x;
  const int node0 = b << 7;
  const int nn = min(128, n - node0);
  const int e0 = bstart[b], e1 = bstart[b + 1];
  __shared__ int dcnt[128], cur[128], scan[128];
  const int tid = threadIdx.x;
  if (tid < 128) dcnt[tid] = 0;
  __syncthreads();
  for (int i = e0 + tid; i < e1; i += 256)
    atomicAdd(&dcnt[packed[i] & 127], 1);
  __syncthreads();
  int v = 0;
  if (tid < 128) {
    v = (tid < nn) ? dcnt[tid] + 1 : 0;  // +1 = self-loop slot
    scan[tid] = v;
  }
  __syncthreads();
  for (int off = 1; off < 128; off <<= 1) {
    int u = 0;
    if (tid < 128 && tid >= off) u = scan[tid - off];
    __syncthreads();
    if (tid < 128) scan[tid] += u;
    __syncthreads();
  }
  if (tid < nn) {
    const int o = e0 + node0 + (scan[tid] - v);  // global CSR offset
    offs[node0 + tid] = o;
    deg[node0 + tid] = dcnt[tid];
    srcs[o] = node0 + tid;  // self-loop first
    cur[tid] = o + 1;
  }
  __syncthreads();
  for (int i = e0 + tid; i < e1; i += 256) {
    const int pv = packed[i];
    const int p = atomicAdd(&cur[pv & 127], 1);
    srcs[p] = pv >> 7;
  }
}

// ---------------- fused GAT aggregation + BN-stats accumulation -------------
// 16 thr/node, 4 nodes/wave, 16 nodes/block. Epilogue reduces per-channel
// sum/sumsq over the block's 16 nodes and atomicAdds into NSLOT-spread stats.
__global__ __launch_bounds__(256) void k_agg(
    const int* __restrict__ offs, const int* __restrict__ deg,
    const int* __restrict__ srcs, const uint4* __restrict__ Hb,
    const float* __restrict__ as_, const float* __restrict__ ad_,
    float* __restrict__ out, float* __restrict__ stats, int n) {
  __shared__ float sblk[4][2][128];
  const int tid = threadIdx.x;
  const int node = blockIdx.x * 16 + (tid >> 4);
  const bool active = node < n;
  const int w = tid >> 6, lane = tid & 63;
  const int t = lane & 15;
  const int th = t >> 2;    // head of my channels
  const int j4 = lane & 3;  // my edge slot per chunk
  const int o0 = active ? offs[node] : 0;
  const int dg = active ? deg[node] + 1 : 0;  // + self-loop
  const float adv = active ? ad_[node * 4 + th] : 0.f;

  float den = 0.f;
  float acc[8];
#pragma unroll
  for (int i = 0; i < 8; ++i) acc[i] = 0.f;

  // prologue: prep chunk 0
  int s = 0;
  float e = 0.f;
  if (j4 < dg) {
    s = srcs[o0 + j4];
    float l = as_[s * 4 + th] + adv;
    l = l >= 0.f ? l : 0.2f * l;
    e = __expf(fminf(l, 80.f));
  }

  for (int base = 0; base < dg; base += 4) {
    int s2 = 0;
    float e2 = 0.f;
    const int jn = base + 4 + j4;
    if (jn < dg) {
      s2 = srcs[o0 + jn];
      float l = as_[s2 * 4 + th] + adv;
      l = l >= 0.f ? l : 0.2f * l;
      e2 = __expf(fminf(l, 80.f));
    }
    den += e;
#pragma unroll
    for (int jj = 0; jj < 4; ++jj) {
      if (base + jj >= dg) break;
      const int ss = __shfl(s, (lane & 48) | jj, 64);
      const float wv = __shfl(e, (lane & ~3) | jj, 64);
      const uint4 hv = Hb[(long)ss * 16 + t];
      acc[0] = fmaf(wv, __uint_as_float(hv.x << 16), acc[0]);
      acc[1] = fmaf(wv, __uint_as_float(hv.x & 0xffff0000u), acc[1]);
      acc[2] = fmaf(wv, __uint_as_float(hv.y << 16), acc[2]);
      acc[3] = fmaf(wv, __uint_as_float(hv.y & 0xffff0000u), acc[3]);
      acc[4] = fmaf(wv, __uint_as_float(hv.z << 16), acc[4]);
      acc[5] = fmaf(wv, __uint_as_float(hv.z & 0xffff0000u), acc[5]);
      acc[6] = fmaf(wv, __uint_as_float(hv.w << 16), acc[6]);
      acc[7] = fmaf(wv, __uint_as_float(hv.w & 0xffff0000u), acc[7]);
    }
    s = s2;
    e = e2;
  }
  den += __shfl_xor(den, 1, 64);
  den += __shfl_xor(den, 2, 64);
  const float invden = 1.f / (den + 1e-16f);
  float sums[8], sqs[8];
#pragma unroll
  for (int i = 0; i < 8; ++i) {
    float v = acc[i] * invden;
    acc[i] = v;
    sums[i] = v;
    sqs[i] = v * v;
  }
  if (active) {
    float4 o0v = make_float4(acc[0], acc[1], acc[2], acc[3]);
    float4 o1v = make_float4(acc[4], acc[5], acc[6], acc[7]);
    ((float4*)out)[(long)node * 32 + t * 2] = o0v;
    ((float4*)out)[(long)node * 32 + t * 2 + 1] = o1v;
  }
  // wave reduce over the wave's 4 nodes (lane>>4 groups)
#pragma unroll
  for (int off = 16; off <= 32; off <<= 1) {
#pragma unroll
    for (int i = 0; i < 8; ++i) {
      sums[i] += __shfl_xor(sums[i], off, 64);
      sqs[i] += __shfl_xor(sqs[i], off, 64);
    }
  }
  if (lane < 16) {
#pragma unroll
    for (int i = 0; i < 8; ++i) {
      sblk[w][0][lane * 8 + i] = sums[i];
      sblk[w][1][lane * 8 + i] = sqs[i];
    }
  }
  __syncthreads();
  {
    const int c = tid & 127, sidx = tid >> 7;
    float v = sblk[0][sidx][c] + sblk[1][sidx][c] + sblk[2][sidx][c] +
              sblk[3][sidx][c];
    atomicAdd(&stats[(blockIdx.x & (NSLOT - 1)) * 256 + sidx * 128 + c], v);
  }
}

// ---------------- BN apply + skip + relu, inline finalize -------------------
__global__ __launch_bounds__(256) void k_bn_apply(
    const float* __restrict__ V, const float* __restrict__ stats,
    const float* __restrict__ gamma, const float* __restrict__ beta,
    float invN, const float* __restrict__ skip, float* __restrict__ Y,
    int total4) {
  __shared__ float ssl[256];
  const int tid = threadIdx.x;
  if (tid < 128) {
    float s = 0.f, s2 = 0.f;
#pragma unroll
    for (int k = 0; k < NSLOT; ++k) {
      s += stats[k * 256 + tid];
      s2 += stats[k * 256 + 128 + tid];
    }
    float mean = s * invN;
    float var = s2 * invN - mean * mean;
    float sc = gamma[tid] * rsqrtf(var + 1e-5f);
    ssl[tid] = sc;
    ssl[128 + tid] = beta[tid] - mean * sc;
  }
  __syncthreads();
  for (int i = blockIdx.x * 256 + tid; i < total4; i += gridDim.x * 256) {
    const int c4 = i & 31;
    float4 v = ((const float4*)V)[i];
    float4 sc = *(const float4*)&ssl[c4 * 4];
    float4 sh = *(const float4*)&ssl[128 + c4 * 4];
    float4 s = ((const float4*)skip)[i];
    float4 y;
    y.x = fmaxf(fmaf(v.x, sc.x, sh.x) + s.x, 0.f);
    y.y = fmaxf(fmaf(v.y, sc.y, sh.y) + s.y, 0.f);
    y.z = fmaxf(fmaf(v.z, sc.z, sh.z) + s.z, 0.f);
    y.w = fmaxf(fmaf(v.w, sc.w, sh.w) + s.w, 0.f);
    ((float4*)Y)[i] = y;
  }
}

extern "C" void kernel_launch(void* const* d_in, const int* in_sizes, int n_in,
                              void* d_out, int out_size, void* d_ws,
                              size_t ws_size, hipStream_t stream) {
  const float* x = (const float*)d_in[0];
  const int* ei = (const int*)d_in[1];
  const float* W1 = (const float*)d_in[2];
  const float* a_src1 = (const float*)d_in[3];
  const float* a_dst1 = (const float*)d_in[4];
  // b1 cancels in BN
  const float* gamma1 = (const float*)d_in[6];
  const float* beta1 = (const float*)d_in[7];
  const float* W2 = (const float*)d_in[8];
  const float* a_src2 = (const float*)d_in[9];
  const float* a_dst2 = (const float*)d_in[10];
  // b2 cancels in BN
  const float* gamma2 = (const float*)d_in[12];
  const float* beta2 = (const float*)d_in[13];

  const int n = in_sizes[0] / 128;
  const int E = in_sizes[1] / 2;
  const int EP = E + n;
  const int NB = (n + 127) >> 7;  // dst buckets (<= MAXNB)
  const int EB = (E + 4095) / 4096;
  const float invN = 1.0f / (float)n;

  char* w = (char*)d_ws;
  const size_t szNC = (size_t)n * 128 * sizeof(float);
  unsigned* Hb = (unsigned*)w;  w += (size_t)n * 64 * sizeof(unsigned);
  float* Bagg = (float*)w;      w += szNC;
  float* as_ = (float*)w;       w += (size_t)n * 4 * sizeof(float);
  float* ad_ = (float*)w;       w += (size_t)n * 4 * sizeof(float);
  int* srcs = (int*)w;          w += (size_t)EP * sizeof(int);
  int* packed = (int*)w;        w += (size_t)E * sizeof(int);
  int* deg = (int*)w;           w += (size_t)n * sizeof(int);
  int* offs = (int*)w;          w += (size_t)n * sizeof(int);
  int* bstart = (int*)w;        w += (size_t)(NB + 1) * sizeof(int);
  int* bcur = (int*)w;          w += (size_t)NB * sizeof(int);
  uint4* Wf1 = (uint4*)w;       w += 2048 * sizeof(uint4);
  uint4* Wf2 = (uint4*)w;       w += 2048 * sizeof(uint4);
  // zero-region: bcnt + stats1 + stats2 (single upfront memset)
  char* zreg = w;
  int* bcnt = (int*)w;          w += (size_t)NB * sizeof(int);
  float* stats1 = (float*)w;    w += NSLOT * 256 * sizeof(float);
  float* stats2 = (float*)w;    w += NSLOT * 256 * sizeof(float);
  const size_t zbytes = (size_t)(w - zreg);

  hipMemsetAsync(zreg, 0, zbytes, stream);

  // ---- W fragment prep (one dispatch for both layers) ----
  k_wprep<<<16, 256, 0, stream>>>(W1, Wf1, W2, Wf2);

  // ---- CSR build (bucket binning; shared by both layers) ----
  k_hist<<<EB, 256, 0, stream>>>(ei, E, NB, bcnt);
  k_bprefix<<<1, 1024, 0, stream>>>(bcnt, NB, bstart, bcur);
  k_scatter<<<EB, 256, 0, stream>>>(ei, E, NB, bcur, packed);
  k_local<<<NB, 256, 0, stream>>>(packed, bstart, n, srcs, offs, deg);

  // ---- layer 1 ----
  k_gemm<<<(n + 63) / 64, 256, 0, stream>>>(x, Wf1, Hb, n, nullptr, nullptr,
                                            nullptr, invN, a_src1, a_dst1,
                                            as_, ad_);
  k_agg<<<(n + 15) / 16, 256, 0, stream>>>(offs, deg, srcs, (const uint4*)Hb,
                                           as_, ad_, Bagg, stats1, n);

  // ---- layer 2 (BN1+ReLU folded into GEMM2; finalize inline) ----
  k_gemm<<<(n + 63) / 64, 256, 0, stream>>>(Bagg, Wf2, Hb, n, stats1, gamma1,
                                            beta1, invN, a_src2, a_dst2, as_,
                                            ad_);
  k_agg<<<(n + 15) / 16, 256, 0, stream>>>(offs, deg, srcs, (const uint4*)Hb,
                                           as_, ad_, Bagg, stats2, n);
  k_bn_apply<<<2048, 256, 0, stream>>>(Bagg, stats2, gamma2, beta2, invN, x,
                                       (float*)d_out, n * 32);
}